// Round 5
// baseline (719.312 us; speedup 1.0000x reference)
//
#include <hip/hip_runtime.h>
#include <stdint.h>

#define NN   8192
#define FIN  128
#define DM   256
#define DI   512
#define DST  16
#define NC   256   // scan chunks
#define CL   32    // chunk length

typedef short bf16x8 __attribute__((ext_vector_type(8)));
typedef float f32x4 __attribute__((ext_vector_type(4)));
union FragU { unsigned u[4]; uint4 u4; bf16x8 v; };

__device__ __forceinline__ unsigned short f2bf(float x){
  unsigned u = __float_as_uint(x);
  return (unsigned short)((u + 0x7FFFu + ((u >> 16) & 1u)) >> 16);
}
__device__ __forceinline__ unsigned pack2(float a, float b){
  return (unsigned)f2bf(a) | ((unsigned)f2bf(b) << 16);
}
// fast round-to-nearest pack (one v_perm for hi16 of both)
__device__ __forceinline__ unsigned pack2rn(float a, float b){
  unsigned ua = __float_as_uint(a) + 0x8000u;
  unsigned ub = __float_as_uint(b) + 0x8000u;
  return __builtin_amdgcn_perm(ub, ua, 0x07060302u);
}
__device__ __forceinline__ uint4 packA8(float4 a, float4 b){
  uint4 w;
  w.x = pack2rn(a.x, a.y); w.y = pack2rn(a.z, a.w);
  w.z = pack2rn(b.x, b.y); w.w = pack2rn(b.z, b.w);
  return w;
}
__device__ __forceinline__ float bf2f(unsigned short u){
  return __uint_as_float(((unsigned)u) << 16);
}
__device__ __forceinline__ float sigmoidf_(float x){ return 1.f / (1.f + __expf(-x)); }
__device__ __forceinline__ f32x4 zero4(){ f32x4 z; z[0]=0.f; z[1]=0.f; z[2]=0.f; z[3]=0.f; return z; }

#define ASYNC16(g, l) __builtin_amdgcn_global_load_lds( \
    (const __attribute__((address_space(1))) void*)(g), \
    (__attribute__((address_space(3))) void*)(l), 16, 0, 0)
#define WAITLGKM0 asm volatile("s_waitcnt lgkmcnt(0)" ::: "memory")
#define BARRIER  asm volatile("s_barrier" ::: "memory")

// ---------------- workspace layout ----------------
constexpr size_t OFF_XWT   = 0;                                  // xw^T bf16 [256][8192]
constexpr size_t OFF_HB    = OFF_XWT   + (size_t)DM*NN*2;        // relu(h) bf16
constexpr size_t OFF_HBNB  = OFF_HB    + (size_t)NN*DM*2;        // BN'd h bf16
constexpr size_t OFF_WINB  = OFF_HBNB  + (size_t)NN*DM*2;        // w_in bf16 [1024][256]
constexpr size_t OFF_WXPB  = OFF_WINB  + (size_t)1024*256*2;     // w_xproj bf16 [48][512]
constexpr size_t OFF_WOUTB = OFF_WXPB  + (size_t)48*512*2;       // w_out bf16 [256][512]
constexpr size_t OFF_XMB   = OFF_WOUTB + (size_t)256*512*2;      // xm bf16 [8192][512]
constexpr size_t OFF_ZB    = OFF_XMB   + (size_t)NN*DI*2;        // z bf16 [8192][512]
constexpr size_t OFF_XCB   = OFF_ZB    + (size_t)NN*DI*2;        // xc bf16
constexpr size_t OFF_XDBL  = OFF_XCB   + (size_t)NN*DI*2;        // x_dbl fp32 [8192][48]
constexpr size_t OFF_DT    = OFF_XDBL  + (size_t)NN*48*4;        // dt fp32 [8192][512]
constexpr size_t OFF_PF    = OFF_DT    + (size_t)NN*DI*4;        // chunk {P,F} float2 [256][8192]
constexpr size_t OFF_CY    = OFF_PF    + (size_t)NC*DI*DST*8;    // carry fp32 [256][8192]
constexpr size_t OFF_YB    = OFF_CY    + (size_t)NC*DI*DST*4;    // gated y bf16
constexpr size_t OFF_BNS   = OFF_YB    + (size_t)NN*DI*2;
constexpr size_t OFF_BNS2  = OFF_BNS   + 256*4;
constexpr size_t WS_NEED   = OFF_BNS2  + 256*4;
// gemm2 fp32 partials [2][8192][256] = 16MB alias onto PF (dead until scanA)
constexpr size_t OFF_HP    = OFF_PF;

// ---------------- prep: fp32 -> bf16 weights ----------------
__global__ __launch_bounds__(256) void prep_kernel(
    const float* __restrict__ w_in, const float* __restrict__ w_xp, const float* __restrict__ w_out,
    unsigned short* __restrict__ o_in, unsigned short* __restrict__ o_xp, unsigned short* __restrict__ o_out)
{
  int i = blockIdx.x * 256 + threadIdx.x;
  if (i < 1024*256) o_in[i]  = f2bf(w_in[i]);
  if (i < 48*512)   o_xp[i]  = f2bf(w_xp[i]);
  if (i < 256*512)  o_out[i] = f2bf(w_out[i]);
}

// ---------------- gemm1: xw = x @ w_gcn, stored transposed bf16 [256][8192] ----------------
__global__ __launch_bounds__(256) void gemm1_kernel(
    const float* __restrict__ x, const float* __restrict__ w, unsigned short* __restrict__ xwT)
{
  __shared__ float xs[16*128];
  const int t = threadIdx.x;
  const int m0 = blockIdx.x * 16;
  {
    int r = t >> 4, c0 = (t & 15) * 8;
    const float* src = x + (size_t)(m0 + r)*FIN + c0;
    *(float4*)&xs[r*128 + c0]     = *(const float4*)src;
    *(float4*)&xs[r*128 + c0 + 4] = *(const float4*)(src + 4);
  }
  __syncthreads();
  const int n = t;
  float acc[16];
  #pragma unroll
  for (int m = 0; m < 16; ++m) acc[m] = 0.f;
  for (int k = 0; k < 128; k += 4){
    float w0 = w[(size_t)k*DM + n];
    float w1 = w[(size_t)(k+1)*DM + n];
    float w2 = w[(size_t)(k+2)*DM + n];
    float w3 = w[(size_t)(k+3)*DM + n];
    #pragma unroll
    for (int m = 0; m < 16; ++m){
      float4 xv = *(const float4*)&xs[m*128 + k];
      acc[m] = fmaf(xv.x, w0, acc[m]);
      acc[m] = fmaf(xv.y, w1, acc[m]);
      acc[m] = fmaf(xv.z, w2, acc[m]);
      acc[m] = fmaf(xv.w, w3, acc[m]);
    }
  }
  unsigned outp[8];
  #pragma unroll
  for (int m = 0; m < 8; ++m) outp[m] = pack2(acc[2*m], acc[2*m+1]);
  unsigned short* dst = xwT + (size_t)n*NN + m0;
  ((uint4*)dst)[0] = *(uint4*)&outp[0];
  ((uint4*)dst)[1] = *(uint4*)&outp[4];
}

// ---------------- gemm2: hp[ks] = adj[:, ks-half] @ xw[ks-half, :] ----------------
// VGPR-staged (NOT lds-DMA: the DMA path is MLP-capped at ~3 B/cy/CU).
// M64 x N256 x BK64, K-split 2 (ks = XCD parity -> 2MB B-slice L2-resident).
// 8 waves, double 40KB LDS, software pipeline: loads k+2 in regs during iter k,
// A converted to bf16 in regs. Raw s_barrier + lgkmcnt only (no vmcnt drain).
__global__ __launch_bounds__(512, 1) void gemm2_kernel(
    const float* __restrict__ adj, const unsigned short* __restrict__ xwT,
    float* __restrict__ hp)
{
  extern __shared__ char lds[];   // 2 bufs x 40960 B: A bf16 [64][64] @0 (8KB), B bf16 [256][64] @8192 (32KB)
  const int t = threadIdx.x;
  const int wave = t >> 6, lane = t & 63, r = lane & 15, q = lane >> 4;
  const int wm = wave & 1, wn = wave >> 1;
  const int mt = (int)blockIdx.x >> 1, ks = (int)blockIdx.x & 1;
  const int m0 = mt * 64;
  const int kb = ks * 4096;

  // A staging: thread -> (row, 8-float segment); rotate-by-row slot swizzle
  const int arow = t >> 3, aseg = t & 7;
  const float* asrc = adj + (size_t)(m0 + arow)*NN + kb + aseg*8;
  const int awOff = (arow*32 + ((aseg + arow) & 7)*4) * 4;
  // B staging: 4 chunks/thread of 8 bf16
  const unsigned short* bsrc[4];
  int bwOff[4];
  #pragma unroll
  for (int j = 0; j < 4; ++j){
    int si = t + 512*j;
    int bn = si >> 3, bc = si & 7;
    bsrc[j]  = xwT + (size_t)bn*NN + kb + bc*8;
    bwOff[j] = 8192 + (bn*32 + ((bc + bn) & 7)*4) * 4;
  }

  f32x4 acc[2][4];
  #pragma unroll
  for (int mi = 0; mi < 2; ++mi)
    #pragma unroll
    for (int ni = 0; ni < 4; ++ni) acc[mi][ni] = zero4();

  // fragment byte offsets (within buffer)
  int aro[2][2], bro[2][4];
  #pragma unroll
  for (int ks2 = 0; ks2 < 2; ++ks2){
    int g = ks2*4 + q;
    #pragma unroll
    for (int mi = 0; mi < 2; ++mi){
      int m = wm*32 + mi*16 + r;
      aro[ks2][mi] = (m*32 + ((g + m) & 7)*4) * 4;
    }
    #pragma unroll
    for (int ni = 0; ni < 4; ++ni){
      int n = wn*64 + ni*16 + r;
      bro[ks2][ni] = 8192 + (n*32 + ((g + n) & 7)*4) * 4;
    }
  }

  // staging registers, 2 banks (set s lives in bank s&1)
  float4 arA[2], arB[2];
  uint4  brr[2][4];

  // prologue: load set0, set1; write set0 -> buf0
  arA[0] = *(const float4*)(asrc);
  arB[0] = *(const float4*)(asrc + 4);
  #pragma unroll
  for (int j = 0; j < 4; ++j) brr[0][j] = *(const uint4*)(bsrc[j]);
  arA[1] = *(const float4*)(asrc + 64);
  arB[1] = *(const float4*)(asrc + 68);
  #pragma unroll
  for (int j = 0; j < 4; ++j) brr[1][j] = *(const uint4*)(bsrc[j] + 64);
  *(uint4*)(lds + awOff) = packA8(arA[0], arB[0]);
  #pragma unroll
  for (int j = 0; j < 4; ++j) *(uint4*)(lds + bwOff[j]) = brr[0][j];
  WAITLGKM0; BARRIER;

  #pragma unroll 2
  for (int k = 0; k < 64; ++k){
    char* Lb = lds + (k & 1)*40960;
    // fragment reads (set k)
    FragU fa[2][2], fb[2][4];
    #pragma unroll
    for (int ks2 = 0; ks2 < 2; ++ks2){
      #pragma unroll
      for (int mi = 0; mi < 2; ++mi) fa[ks2][mi].u4 = *(const uint4*)(Lb + aro[ks2][mi]);
      #pragma unroll
      for (int ni = 0; ni < 4; ++ni) fb[ks2][ni].u4 = *(const uint4*)(Lb + bro[ks2][ni]);
    }
    // issue loads for set k+2 into bank k&1 (regs already consumed by iter k-1's write)
    if (k + 2 < 64){
      int off = (k + 2) * 64;
      arA[k & 1] = *(const float4*)(asrc + off);
      arB[k & 1] = *(const float4*)(asrc + off + 4);
      #pragma unroll
      for (int j = 0; j < 4; ++j) brr[k & 1][j] = *(const uint4*)(bsrc[j] + off);
    }
    // write set k+1 -> other buffer
    if (k + 1 < 64){
      char* Lw = lds + ((k + 1) & 1)*40960;
      const int b = (k + 1) & 1;
      *(uint4*)(Lw + awOff) = packA8(arA[b], arB[b]);
      #pragma unroll
      for (int j = 0; j < 4; ++j) *(uint4*)(Lw + bwOff[j]) = brr[b][j];
    }
    // MFMA
    #pragma unroll
    for (int ks2 = 0; ks2 < 2; ++ks2)
      #pragma unroll
      for (int mi = 0; mi < 2; ++mi)
        #pragma unroll
        for (int ni = 0; ni < 4; ++ni)
          acc[mi][ni] = __builtin_amdgcn_mfma_f32_16x16x32_bf16(fa[ks2][mi].v, fb[ks2][ni].v, acc[mi][ni], 0, 0, 0);
    WAITLGKM0; BARRIER;
  }

  float* hpo = hp + (size_t)ks * ((size_t)NN * DM);
  #pragma unroll
  for (int mi = 0; mi < 2; ++mi)
    #pragma unroll
    for (int ni = 0; ni < 4; ++ni){
      const int n = wn*64 + ni*16 + r;
      #pragma unroll
      for (int jr = 0; jr < 4; ++jr){
        const int m = m0 + wm*32 + mi*16 + q*4 + jr;
        hpo[(size_t)m*DM + n] = acc[mi][ni][jr];
      }
    }
}

// ---------------- hred: h = relu(hp0+hp1+bias) -> bf16, + BN stats ----------------
__global__ __launch_bounds__(256) void hred_kernel(
    const float* __restrict__ hp, const float* __restrict__ b_gcn,
    unsigned short* __restrict__ hb, float* __restrict__ bns, float* __restrict__ bns2)
{
  const size_t NND = (size_t)NN * DM;
  const int c = threadIdx.x;
  const int m0 = blockIdx.x * 32;
  const float bias = b_gcn[c];
  float s1 = 0.f, s2 = 0.f;
  #pragma unroll 8
  for (int rr = 0; rr < 32; ++rr){
    size_t idx = (size_t)(m0 + rr)*DM + c;
    float v = hp[idx] + hp[NND + idx] + bias;
    v = fmaxf(v, 0.f);
    hb[idx] = f2bf(v);
    s1 += v; s2 += v*v;
  }
  atomicAdd(bns + c, s1);
  atomicAdd(bns2 + c, s2);
}

// ---------------- bnapply: hbnb = BN(hb) bf16 ----------------
__global__ __launch_bounds__(256) void bnapply_kernel(
    const unsigned short* __restrict__ hb, const float* __restrict__ s1, const float* __restrict__ s2,
    const float* __restrict__ gamma, const float* __restrict__ beta,
    unsigned short* __restrict__ hbnb)
{
  int base = (blockIdx.x*256 + threadIdx.x) * 2;
  int c0 = base & (DM - 1);
  ushort2 hv = *(const ushort2*)(hb + base);
  float mA = s1[c0] * (1.f/NN),   mB = s1[c0+1] * (1.f/NN);
  float vA = s2[c0] * (1.f/NN) - mA*mA, vB = s2[c0+1] * (1.f/NN) - mB*mB;
  float iA = rsqrtf(vA + 1e-5f), iB = rsqrtf(vB + 1e-5f);
  float a = (bf2f(hv.x) - mA)*iA*gamma[c0]   + beta[c0];
  float b = (bf2f(hv.y) - mB)*iB*gamma[c0+1] + beta[c0+1];
  ushort2 o; o.x = f2bf(a); o.y = f2bf(b);
  *(ushort2*)(hbnb + base) = o;
}

// ---------------- gemm3: [xm|z] = hbnb @ w_in^T (M=8192,K=256,N=1024), bf16 out ----------------
__global__ __launch_bounds__(256) void gemm3_kernel(
    const unsigned short* __restrict__ Ab, const unsigned short* __restrict__ Wb,
    unsigned short* __restrict__ xmb, unsigned short* __restrict__ zb)
{
  __shared__ uint4 alds[2048];  // 64 rows x 32 slots (swizzled), 32 KB
  const int t = threadIdx.x;
  const int wave = t >> 6, lane = t & 63, r = lane & 15, q = lane >> 4;
  const int mb = ((int)blockIdx.x & 127) * 64;
  const int nb = ((int)blockIdx.x >> 7) * 128;
  const int wm = wave & 1, wn = wave >> 1;

  #pragma unroll
  for (int j = 0; j < 8; ++j){
    int si = j*256 + t;
    int row = si >> 5, dg = si & 31;
    int sg = dg ^ (row & 31);
    ASYNC16(Ab + (size_t)(mb + row)*DM + sg*8, (char*)alds + si*16);
  }
  __syncthreads();

  f32x4 acc[2][4];
  #pragma unroll
  for (int mi = 0; mi < 2; ++mi)
    #pragma unroll
    for (int ni = 0; ni < 4; ++ni) acc[mi][ni] = zero4();

  const unsigned short* bp[4];
  #pragma unroll
  for (int ni = 0; ni < 4; ++ni)
    bp[ni] = Wb + (size_t)(nb + wn*64 + ni*16 + r)*DM + q*8;
  FragU fb[4];
  #pragma unroll
  for (int ni = 0; ni < 4; ++ni) fb[ni].u4 = *(const uint4*)bp[ni];

  #pragma unroll
  for (int it = 0; it < 8; ++it){
    FragU fbn[4];
    if (it < 7){
      #pragma unroll
      for (int ni = 0; ni < 4; ++ni) fbn[ni].u4 = *(const uint4*)(bp[ni] + (it+1)*32);
    }
    FragU fa[2];
    #pragma unroll
    for (int mi = 0; mi < 2; ++mi){
      int row = wm*32 + mi*16 + r;
      int g = it*4 + q;
      fa[mi].u4 = alds[row*32 + (g ^ (row & 31))];
    }
    #pragma unroll
    for (int mi = 0; mi < 2; ++mi)
      #pragma unroll
      for (int ni = 0; ni < 4; ++ni)
        acc[mi][ni] = __builtin_amdgcn_mfma_f32_16x16x32_bf16(fa[mi].v, fb[ni].v, acc[mi][ni], 0, 0, 0);
    if (it < 7){
      #pragma unroll
      for (int ni = 0; ni < 4; ++ni) fb[ni] = fbn[ni];
    }
  }
  #pragma unroll
  for (int mi = 0; mi < 2; ++mi)
    #pragma unroll
    for (int ni = 0; ni < 4; ++ni){
      int nc = nb + wn*64 + ni*16 + r;
      unsigned short* dst = (nc < 512) ? (xmb + nc) : (zb + (nc - 512));
      #pragma unroll
      for (int jr = 0; jr < 4; ++jr){
        int m = mb + wm*32 + mi*16 + q*4 + jr;
        dst[(size_t)m*DI] = f2bf(acc[mi][ni][jr]);
      }
    }
}

// ---------------- conv: depthwise causal D=4 + SiLU, bf16 out ----------------
__global__ __launch_bounds__(256) void conv_kernel(
    const unsigned short* __restrict__ xmb, const float* __restrict__ conv_w, const float* __restrict__ conv_b,
    unsigned short* __restrict__ xcb)
{
  const int d0 = threadIdx.x * 2;
  const int n0 = blockIdx.x * 32;
  float4 wa = *(const float4*)(conv_w + (size_t)d0*4);
  float4 wb = *(const float4*)(conv_w + (size_t)d0*4 + 4);
  float2 bias = *(const float2*)(conv_b + d0);
  float x0a=0.f,x1a=0.f,x2a=0.f, x0b=0.f,x1b=0.f,x2b=0.f;
  #pragma unroll
  for (int j = 0; j < 3; ++j){
    int n = n0 - 3 + j;
    float va = 0.f, vb = 0.f;
    if (n >= 0){
      ushort2 u = *(const ushort2*)(xmb + (size_t)n*DI + d0);
      va = bf2f(u.x); vb = bf2f(u.y);
    }
    if (j == 0){ x0a = va; x0b = vb; }
    else if (j == 1){ x1a = va; x1b = vb; }
    else { x2a = va; x2b = vb; }
  }
  for (int j = 0; j < 32; ++j){
    int n = n0 + j;
    ushort2 u = *(const ushort2*)(xmb + (size_t)n*DI + d0);
    float x3a = bf2f(u.x), x3b = bf2f(u.y);
    float sa = bias.x + wa.x*x0a + wa.y*x1a + wa.z*x2a + wa.w*x3a;
    float sb = bias.y + wb.x*x0b + wb.y*x1b + wb.z*x2b + wb.w*x3b;
    float va = sa * sigmoidf_(sa);
    float vb = sb * sigmoidf_(sb);
    ushort2 o; o.x = f2bf(va); o.y = f2bf(vb);
    *(ushort2*)(xcb + (size_t)n*DI + d0) = o;
    x0a=x1a; x1a=x2a; x2a=x3a;
    x0b=x1b; x1b=x2b; x2b=x3b;
  }
}

// ---------------- gemm4: x_dbl = xc @ w_xproj^T (M=8192,K=512,N=48) + fused dt ----------------
__global__ __launch_bounds__(256) void gemm4_kernel(
    const unsigned short* __restrict__ Ab, const unsigned short* __restrict__ Wb,
    const float* __restrict__ w_dt, const float* __restrict__ b_dt,
    float* __restrict__ xdbl, float* __restrict__ dt)
{
  __shared__ uint4 alds[2048];  // 32 rows x 64 slots, 32 KB
  __shared__ float xr2[32*16];  // dt_r staging for fused dt
  const int t = threadIdx.x;
  const int wave = t >> 6, lane = t & 63, r = lane & 15, q = lane >> 4;
  const int m0 = (int)blockIdx.x * 32;
  #pragma unroll
  for (int j = 0; j < 8; ++j){
    int si = j*256 + t;
    int row = si >> 6, dg = si & 63;
    int sg = dg ^ (row & 31);
    ASYNC16(Ab + (size_t)(m0 + row)*DI + sg*8, (char*)alds + si*16);
  }
  __syncthreads();
  f32x4 acc[2][3];
  #pragma unroll
  for (int mi = 0; mi < 2; ++mi)
    #pragma unroll
    for (int ni = 0; ni < 3; ++ni) acc[mi][ni] = zero4();
  const int kq = wave * 128;
  const unsigned short* bp[3];
  #pragma unroll
  for (int ni = 0; ni < 3; ++ni) bp[ni] = Wb + (size_t)(ni*16 + r)*DI + kq + q*8;
  FragU fb[3];
  #pragma unroll
  for (int ni = 0; ni < 3; ++ni) fb[ni].u4 = *(const uint4*)bp[ni];
  #pragma unroll
  for (int it = 0; it < 4; ++it){
    FragU fbn[3];
    if (it < 3){
      #pragma unroll
      for (int ni = 0; ni < 3; ++ni) fbn[ni].u4 = *(const uint4*)(bp[ni] + (it+1)*32);
    }
    FragU fa[2];
    #pragma unroll
    for (int mi = 0; mi < 2; ++mi){
      int row = mi*16 + r;
      int g = (kq >> 3) + it*4 + q;
      fa[mi].u4 = alds[row*64 + (g ^ (row & 31))];
    }
    #pragma unroll
    for (int mi = 0; mi < 2; ++mi)
      #pragma unroll
      for (int ni = 0; ni < 3; ++ni)
        acc[mi][ni] = __builtin_amdgcn_mfma_f32_16x16x32_bf16(fa[mi].v, fb[ni].v, acc[mi][ni], 0, 0, 0);
    if (it < 3){
      #pragma unroll
      for (int ni = 0; ni < 3; ++ni) fb[ni] = fbn[ni];
    }
  }
  __syncthreads();
  float* red = (float*)alds;
  if (wave > 0){
    int base = ((wave - 1)*64 + lane)*24;
    #pragma unroll
    for (int mi = 0; mi < 2; ++mi)
      #pragma unroll
      for (int ni = 0; ni < 3; ++ni)
        #pragma unroll
        for (int jr = 0; jr < 4; ++jr)
          red[base + (mi*3 + ni)*4 + jr] = acc[mi][ni][jr];
  }
  __syncthreads();
  if (wave == 0){
    #pragma unroll
    for (int w = 0; w < 3; ++w){
      int base = (w*64 + lane)*24;
      #pragma unroll
      for (int mi = 0; mi < 2; ++mi)
        #pragma unroll
        for (int ni = 0; ni < 3; ++ni)
          #pragma unroll
          for (int jr = 0; jr < 4; ++jr)
            acc[mi][ni][jr] += red[base + (mi*3 + ni)*4 + jr];
    }
    #pragma unroll
    for (int mi = 0; mi < 2; ++mi)
      #pragma unroll
      for (int ni = 0; ni < 3; ++ni)
        #pragma unroll
        for (int jr = 0; jr < 4; ++jr)
          xdbl[(size_t)(m0 + mi*16 + q*4 + jr)*48 + ni*16 + r] = acc[mi][ni][jr];
    // stage dt_r (cols 0..15) for fused dt
    #pragma unroll
    for (int mi = 0; mi < 2; ++mi)
      #pragma unroll
      for (int jr = 0; jr < 4; ++jr)
        xr2[(mi*16 + q*4 + jr)*16 + r] = acc[mi][0][jr];
  }
  __syncthreads();
  // fused dt: softplus(dt_r @ w_dt^T + b_dt) for rows m0..m0+31, all 512 d
  const int d0 = t * 2;
  const float4* wp0 = (const float4*)(w_dt + (size_t)d0*16);
  const float4* wp1 = (const float4*)(w_dt + (size_t)(d0+1)*16);
  float4 wA0 = wp0[0], wA1 = wp0[1], wA2 = wp0[2], wA3 = wp0[3];
  float4 wB0 = wp1[0], wB1 = wp1[1], wB2 = wp1[2], wB3 = wp1[3];
  float2 bb = *(const float2*)(b_dt + d0);
  for (int j = 0; j < 32; ++j){
    const float4* xp = (const float4*)(xr2 + j*16);
    float4 a0 = xp[0], a1 = xp[1], a2 = xp[2], a3 = xp[3];
    float sA = bb.x, sB = bb.y;
    sA += wA0.x*a0.x + wA0.y*a0.y + wA0.z*a0.z + wA0.w*a0.w;
    sA += wA1.x*a1.x + wA1.y*a1.y + wA1.z*a1.z + wA1.w*a1.w;
    sA += wA2.x*a2.x + wA2.y*a2.y + wA2.z*a2.z + wA2.w*a2.w;
    sA += wA3.x*a3.x + wA3.y*a3.y + wA3.z*a3.z + wA3.w*a3.w;
    sB += wB0.x*a0.x + wB0.y*a0.y + wB0.z*a0.z + wB0.w*a0.w;
    sB += wB1.x*a1.x + wB1.y*a1.y + wB1.z*a1.z + wB1.w*a1.w;
    sB += wB2.x*a2.x + wB2.y*a2.y + wB2.z*a2.z + wB2.w*a2.w;
    sB += wB3.x*a3.x + wB3.y*a3.y + wB3.z*a3.z + wB3.w*a3.w;
    float oA = (sA > 20.f) ? sA : log1pf(__expf(sA));
    float oB = (sB > 20.f) ? sB : log1pf(__expf(sB));
    *(float2*)(dt + (size_t)(m0 + j)*DI + d0) = make_float2(oA, oB);
  }
}

// ---------------- scanA: per-chunk local recurrence -> interleaved {P,F} ----------------
__global__ __launch_bounds__(256) void scanA_kernel(
    const float* __restrict__ dt, const unsigned short* __restrict__ xcb,
    const float* __restrict__ xdbl, const float* __restrict__ A_log,
    float2* __restrict__ PF)
{
  __shared__ float Bs[CL*DST];
  const int t = threadIdx.x;
  const int c = (int)blockIdx.x >> 1;
  const int d = (((int)blockIdx.x & 1) << 8) + t;
  #pragma unroll
  for (int j = 0; j < 2; ++j){
    int idx = t + 256*j;
    Bs[idx] = xdbl[(size_t)(c*CL + (idx >> 4))*48 + 16 + (idx & 15)];
  }
  __syncthreads();
  float Av[DST], hs[DST];
  {
    const float4* Ap = (const float4*)(A_log + (size_t)d*DST);
    #pragma unroll
    for (int s4 = 0; s4 < 4; ++s4){
      float4 a4 = Ap[s4];
      Av[s4*4+0] = -__expf(a4.x); Av[s4*4+1] = -__expf(a4.y);
      Av[s4*4+2] = -__expf(a4.z); Av[s4*4+3] = -__expf(a4.w);
    }
  }
  #pragma unroll
  for (int s = 0; s < DST; ++s) hs[s] = 0.f;
  float sdt = 0.f;
  const size_t rb = (size_t)c*CL*DI + d;
  float dtv = dt[rb], xcv = bf2f(xcb[rb]);
  for (int tt = 0; tt < CL; ++tt){
    float dtn = 0.f, xcn = 0.f;
    if (tt + 1 < CL){
      dtn = dt[rb + (size_t)(tt+1)*DI];
      xcn = bf2f(xcb[rb + (size_t)(tt+1)*DI]);
    }
    float u = dtv * xcv;
    sdt += dtv;
    float bv[DST];
    *(float4*)&bv[0]  = *(const float4*)&Bs[tt*16];
    *(float4*)&bv[4]  = *(const float4*)&Bs[tt*16 + 4];
    *(float4*)&bv[8]  = *(const float4*)&Bs[tt*16 + 8];
    *(float4*)&bv[12] = *(const float4*)&Bs[tt*16 + 12];
    #pragma unroll
    for (int s = 0; s < DST; ++s)
      hs[s] = __expf(dtv * Av[s]) * hs[s] + u * bv[s];
    dtv = dtn; xcv = xcn;
  }
  float4* out = (float4*)(PF + (size_t)c*(DI*DST) + (size_t)d*DST);
  #pragma unroll
  for (int j = 0; j < 8; ++j){
    float4 v;
    v.x = __expf(Av[2*j] * sdt);   v.y = hs[2*j];
    v.z = __expf(Av[2*j+1] * sdt); v.w = hs[2*j+1];
    out[j] = v;
  }
}

// ---------------- scanB: sequential carry across 256 chunks, batched prefetch ----------------
__global__ __launch_bounds__(128) void scanB_kernel(
    const float2* __restrict__ PF, float* __restrict__ Cy)
{
  const int ds = (int)blockIdx.x*128 + (int)threadIdx.x;
  float2 A0[16], A1[16];
  #pragma unroll
  for (int j = 0; j < 16; ++j) A0[j] = PF[(size_t)j*8192 + ds];
  #pragma unroll
  for (int j = 0; j < 16; ++j) A1[j] = PF[(size_t)(16 + j)*8192 + ds];
  float cy = 0.f;
  Cy[ds] = 0.f;
  #pragma unroll
  for (int g = 0; g < 16; ++g){
    #pragma unroll
    for (int j = 0; j < 16; ++j){
      int i = g*16 + j;
      if (i < NC - 1){
        float2 pf = (g & 1) ? A1[j] : A0[j];
        cy = pf.x * cy + pf.y;
        Cy[(size_t)(i + 1)*8192 + ds] = cy;
      }
    }
    int gn = g + 2;
    if (gn < 16){
      #pragma unroll
      for (int j = 0; j < 16; ++j){
        float2 v = PF[(size_t)(gn*16 + j)*8192 + ds];
        if (g & 1) A1[j] = v; else A0[j] = v;
      }
    }
  }
}

// ---------------- scanC: recompute with carry, emit gated y (bf16) ----------------
__global__ __launch_bounds__(256) void scanC_kernel(
    const float* __restrict__ dt, const unsigned short* __restrict__ xcb,
    const float* __restrict__ xdbl, const float* __restrict__ A_log,
    const float* __restrict__ Cy, const float* __restrict__ Dskip,
    const unsigned short* __restrict__ zb, unsigned short* __restrict__ yb)
{
  __shared__ float Bs[CL*DST];
  __shared__ float Cs[CL*DST];
  const int t = threadIdx.x;
  const int c = (int)blockIdx.x >> 1;
  const int d = (((int)blockIdx.x & 1) << 8) + t;
  #pragma unroll
  for (int j = 0; j < 2; ++j){
    int idx = t + 256*j;
    int tg = c*CL + (idx >> 4);
    Bs[idx] = xdbl[(size_t)tg*48 + 16 + (idx & 15)];
    Cs[idx] = xdbl[(size_t)tg*48 + 32 + (idx & 15)];
  }
  __syncthreads();
  float Av[DST], hs[DST];
  {
    const float4* Ap = (const float4*)(A_log + (size_t)d*DST);
    #pragma unroll
    for (int s4 = 0; s4 < 4; ++s4){
      float4 a4 = Ap[s4];
      Av[s4*4+0] = -__expf(a4.x); Av[s4*4+1] = -__expf(a4.y);
      Av[s4*4+2] = -__expf(a4.z); Av[s4*4+3] = -__expf(a4.w);
    }
  }
  {
    const float4* hp4 = (const float4*)(Cy + (size_t)c*(DI*DST) + (size_t)d*DST);
    #pragma unroll
    for (int s4 = 0; s4 < 4; ++s4){
      float4 h4 = hp4[s4];
      hs[s4*4+0] = h4.x; hs[s4*4+1] = h4.y; hs[s4*4+2] = h4.z; hs[s4*4+3] = h4.w;
    }
  }
  const float Dv = Dskip[d];
  const size_t rb = (size_t)c*CL*DI + d;
  float dtv = dt[rb], xcv = bf2f(xcb[rb]);
  unsigned short zv0 = zb[rb];
  for (int tt = 0; tt < CL; ++tt){
    float dtn = 0.f, xcn = 0.f;
    unsigned short zn = 0;
    if (tt + 1 < CL){
      dtn = dt[rb + (size_t)(tt+1)*DI];
      xcn = bf2f(xcb[rb + (size_t)(tt+1)*DI]);
      zn  = zb[rb + (size_t)(tt+1)*DI];
    }
    float u = dtv * xcv;
    float bv[DST], cv[DST];
    *(float4*)&bv[0]  = *(const float4*)&Bs[tt*16];
    *(float4*)&bv[4]  = *(const float4*)&Bs[tt*16 + 4];
    *(float4*)&bv[8]  = *(const float4*)&Bs[tt*16 + 8];
    *(float4*)&bv[12] = *(const float4*)&Bs[tt*16 + 12];
    *(float4*)&cv[0]  = *(const float4*)&Cs[tt*16];
    *(float4*)&cv[4]  = *(const float4*)&Cs[tt*16 + 4];
    *(float4*)&cv[8]  = *(const float4*)&Cs[tt*16 + 8];
    *(float4*)&cv[12] = *(const float4*)&Cs[tt*16 + 12];
    float y0 = 0.f, y1 = 0.f;
    #pragma unroll
    for (int s = 0; s < DST; s += 2){
      hs[s]   = __expf(dtv * Av[s])   * hs[s]   + u * bv[s];
      hs[s+1] = __expf(dtv * Av[s+1]) * hs[s+1] + u * bv[s+1];
      y0 += hs[s]   * cv[s];
      y1 += hs[s+1] * cv[s+1];
    }
    float z = bf2f(zv0);
    float yf = ((y0 + y1) + Dv * xcv) * (z * sigmoidf_(z));
    yb[rb + (size_t)tt*DI] = f2bf(yf);
    dtv = dtn; xcv = xcn; zv0 = zn;
  }
}

// ---------------- gemm5: out = y @ w_out^T + hbn (M=8192,K=512,N=256) ----------------
__global__ __launch_bounds__(512) void gemm5_kernel(
    const unsigned short* __restrict__ yb, const unsigned short* __restrict__ Wb,
    const unsigned short* __restrict__ hbnb, float* __restrict__ out)
{
  __shared__ uint4 alds[2048];  // 32 rows x 64 slots, 32 KB
  const int t = threadIdx.x;
  const int wave = t >> 6, lane = t & 63, r = lane & 15, q = lane >> 4;
  const int m0 = (int)blockIdx.x * 32;
  #pragma unroll
  for (int j = 0; j < 4; ++j){
    int si = j*512 + t;
    int row = si >> 6, dg = si & 63;
    int sg = dg ^ (row & 31);
    ASYNC16(yb + (size_t)(m0 + row)*DI + sg*8, (char*)alds + si*16);
  }
  __syncthreads();
  f32x4 acc[2][2];
  #pragma unroll
  for (int mi = 0; mi < 2; ++mi)
    #pragma unroll
    for (int ni = 0; ni < 2; ++ni) acc[mi][ni] = zero4();
  const int nw = wave * 32;
  const unsigned short* bp0 = Wb + (size_t)(nw + r)*DI + q*8;
  const unsigned short* bp1 = Wb + (size_t)(nw + 16 + r)*DI + q*8;
  FragU fb0, fb1;
  fb0.u4 = *(const uint4*)bp0;
  fb1.u4 = *(const uint4*)bp1;
  #pragma unroll
  for (int it = 0; it < 16; ++it){
    FragU fn0, fn1;
    if (it < 15){
      fn0.u4 = *(const uint4*)(bp0 + (it+1)*32);
      fn1.u4 = *(const uint4*)(bp1 + (it+1)*32);
    }
    FragU fa[2];
    #pragma unroll
    for (int mi = 0; mi < 2; ++mi){
      int row = mi*16 + r;
      int g = it*4 + q;
      fa[mi].u4 = alds[row*64 + (g ^ (row & 31))];
    }
    acc[0][0] = __builtin_amdgcn_mfma_f32_16x16x32_bf16(fa[0].v, fb0.v, acc[0][0], 0, 0, 0);
    acc[0][1] = __builtin_amdgcn_mfma_f32_16x16x32_bf16(fa[0].v, fb1.v, acc[0][1], 0, 0, 0);
    acc[1][0] = __builtin_amdgcn_mfma_f32_16x16x32_bf16(fa[1].v, fb0.v, acc[1][0], 0, 0, 0);
    acc[1][1] = __builtin_amdgcn_mfma_f32_16x16x32_bf16(fa[1].v, fb1.v, acc[1][1], 0, 0, 0);
    if (it < 15){ fb0 = fn0; fb1 = fn1; }
  }
  #pragma unroll
  for (int mi = 0; mi < 2; ++mi)
    #pragma unroll
    for (int ni = 0; ni < 2; ++ni){
      const int n = nw + ni*16 + r;
      #pragma unroll
      for (int jr = 0; jr < 4; ++jr){
        const int m = m0 + mi*16 + q*4 + jr;
        size_t idx = (size_t)m*DM + n;
        out[idx] = acc[mi][ni][jr] + bf2f(hbnb[idx]);
      }
    }
}

// ---------------- launch ----------------
extern "C" void kernel_launch(void* const* d_in, const int* in_sizes, int n_in,
                              void* d_out, int out_size, void* d_ws, size_t ws_size,
                              hipStream_t stream)
{
  const float* x      = (const float*)d_in[0];
  const float* adj    = (const float*)d_in[1];
  const float* w_gcn  = (const float*)d_in[2];
  const float* b_gcn  = (const float*)d_in[3];
  const float* gamma  = (const float*)d_in[4];
  const float* beta   = (const float*)d_in[5];
  const float* w_in   = (const float*)d_in[6];
  const float* conv_w = (const float*)d_in[7];
  const float* conv_b = (const float*)d_in[8];
  const float* w_xp   = (const float*)d_in[9];
  const float* w_dt   = (const float*)d_in[10];
  const float* b_dt   = (const float*)d_in[11];
  const float* A_log  = (const float*)d_in[12];
  const float* D_skip = (const float*)d_in[13];
  const float* w_out  = (const float*)d_in[14];
  float* out = (float*)d_out;
  char* ws = (char*)d_ws;
  if (ws_size < WS_NEED) return;

  unsigned short* xwT   = (unsigned short*)(ws + OFF_XWT);
  float*          hp    = (float*)(ws + OFF_HP);
  unsigned short* hb    = (unsigned short*)(ws + OFF_HB);
  unsigned short* hbnb  = (unsigned short*)(ws + OFF_HBNB);
  unsigned short* winb  = (unsigned short*)(ws + OFF_WINB);
  unsigned short* wxpb  = (unsigned short*)(ws + OFF_WXPB);
  unsigned short* woutb = (unsigned short*)(ws + OFF_WOUTB);
  unsigned short* xmb   = (unsigned short*)(ws + OFF_XMB);
  unsigned short* zb    = (unsigned short*)(ws + OFF_ZB);
  unsigned short* xcb   = (unsigned short*)(ws + OFF_XCB);
  float*          xdbl  = (float*)(ws + OFF_XDBL);
  float*          dtb   = (float*)(ws + OFF_DT);
  float2*         PF    = (float2*)(ws + OFF_PF);
  float*          Cy    = (float*)(ws + OFF_CY);
  unsigned short* yb    = (unsigned short*)(ws + OFF_YB);
  float*          bns   = (float*)(ws + OFF_BNS);
  float*          bns2  = (float*)(ws + OFF_BNS2);

  hipMemsetAsync(bns, 0, 2*256*sizeof(float), stream);

  // 80KB dynamic LDS for gemm2 (8 waves, 1 block/CU)
  hipFuncSetAttribute((const void*)gemm2_kernel,
                      hipFuncAttributeMaxDynamicSharedMemorySize, 81920);

  prep_kernel   <<<1024, 256, 0, stream>>>(w_in, w_xp, w_out, winb, wxpb, woutb);
  gemm1_kernel  <<<512,  256, 0, stream>>>(x, w_gcn, xwT);
  gemm2_kernel  <<<256,  512, 81920, stream>>>(adj, xwT, hp);
  hred_kernel   <<<256,  256, 0, stream>>>(hp, b_gcn, hb, bns, bns2);
  bnapply_kernel<<<4096, 256, 0, stream>>>(hb, bns, bns2, gamma, beta, hbnb);
  gemm3_kernel  <<<1024, 256, 0, stream>>>(hbnb, winb, xmb, zb);
  conv_kernel   <<<256,  256, 0, stream>>>(xmb, conv_w, conv_b, xcb);
  gemm4_kernel  <<<256,  256, 0, stream>>>(xcb, wxpb, w_dt, b_dt, xdbl, dtb);
  scanA_kernel  <<<512,  256, 0, stream>>>(dtb, xcb, xdbl, A_log, PF);
  scanB_kernel  <<<64,   128, 0, stream>>>(PF, Cy);
  scanC_kernel  <<<512,  256, 0, stream>>>(dtb, xcb, xdbl, A_log, Cy, D_skip, zb, yb);
  gemm5_kernel  <<<256,  512, 0, stream>>>(yb, woutb, hbnb, out);
}

// Round 6
// 705.887 us; speedup vs baseline: 1.0190x; 1.0190x over previous
//
#include <hip/hip_runtime.h>
#include <stdint.h>

#define NN   8192
#define FIN  128
#define DM   256
#define DI   512
#define DST  16
#define NC   256   // scan chunks
#define CL   32    // chunk length

typedef short bf16x8 __attribute__((ext_vector_type(8)));
typedef float f32x4 __attribute__((ext_vector_type(4)));
union FragU { unsigned u[4]; uint4 u4; bf16x8 v; };

__device__ __forceinline__ unsigned short f2bf(float x){
  unsigned u = __float_as_uint(x);
  return (unsigned short)((u + 0x7FFFu + ((u >> 16) & 1u)) >> 16);
}
__device__ __forceinline__ unsigned pack2(float a, float b){
  return (unsigned)f2bf(a) | ((unsigned)f2bf(b) << 16);
}
// fast round-to-nearest pack (one v_perm for hi16 of both)
__device__ __forceinline__ unsigned pack2rn(float a, float b){
  unsigned ua = __float_as_uint(a) + 0x8000u;
  unsigned ub = __float_as_uint(b) + 0x8000u;
  return __builtin_amdgcn_perm(ub, ua, 0x07060302u);
}
__device__ __forceinline__ float bf2f(unsigned short u){
  return __uint_as_float(((unsigned)u) << 16);
}
__device__ __forceinline__ float sigmoidf_(float x){ return 1.f / (1.f + __expf(-x)); }
__device__ __forceinline__ f32x4 zero4(){ f32x4 z; z[0]=0.f; z[1]=0.f; z[2]=0.f; z[3]=0.f; return z; }

#define ASYNC16(g, l) __builtin_amdgcn_global_load_lds( \
    (const __attribute__((address_space(1))) void*)(g), \
    (__attribute__((address_space(3))) void*)(l), 16, 0, 0)

// ---------------- workspace layout ----------------
constexpr size_t OFF_XWT   = 0;                                  // xw bf16 tiled [1024][256][8] (4MB)
constexpr size_t OFF_HB    = OFF_XWT   + (size_t)DM*NN*2;        // relu(h) bf16 [8192][256]
constexpr size_t OFF_WINB  = OFF_HB    + (size_t)NN*DM*2;        // w_in bf16 [1024][256]
constexpr size_t OFF_WIN2  = OFF_WINB  + (size_t)1024*256*2;     // BN-folded w_in bf16
constexpr size_t OFF_BIN   = OFF_WIN2  + (size_t)1024*256*2;     // folded bias fp32 [1024]
constexpr size_t OFF_AB    = OFF_BIN   + 1024*4;                 // BN a[256], b[256] fp32
constexpr size_t OFF_WXPB  = OFF_AB    + 512*4;                  // w_xproj bf16 [48][512]
constexpr size_t OFF_WOUTB = OFF_WXPB  + (size_t)48*512*2;       // w_out bf16 [256][512]
constexpr size_t OFF_XMB   = OFF_WOUTB + (size_t)256*512*2;      // xm bf16 [8192][512]
constexpr size_t OFF_ZB    = OFF_XMB   + (size_t)NN*DI*2;        // z bf16 [8192][512]
constexpr size_t OFF_XCB   = OFF_ZB    + (size_t)NN*DI*2;        // xc bf16
constexpr size_t OFF_XDBL  = OFF_XCB   + (size_t)NN*DI*2;        // x_dbl fp32 [8192][48]
constexpr size_t OFF_DT    = OFF_XDBL  + (size_t)NN*48*4;        // dt fp32 [8192][512]
constexpr size_t OFF_PF    = OFF_DT    + (size_t)NN*DI*4;        // chunk {P,F} float2 [256][8192]
constexpr size_t OFF_CY    = OFF_PF    + (size_t)NC*DI*DST*8;    // carry fp32 [256][8192]
constexpr size_t OFF_YB    = OFF_CY    + (size_t)NC*DI*DST*4;    // gated y bf16
constexpr size_t OFF_BNS   = OFF_YB    + (size_t)NN*DI*2;
constexpr size_t OFF_BNS2  = OFF_BNS   + 256*4;
constexpr size_t WS_NEED   = OFF_BNS2  + 256*4;
// gemm2 fp32 partials [2][8192][256] = 16MB alias onto PF (dead until scanA)
constexpr size_t OFF_HP    = OFF_PF;

// ---------------- prep: fp32 -> bf16 weights ----------------
__global__ __launch_bounds__(256) void prep_kernel(
    const float* __restrict__ w_in, const float* __restrict__ w_xp, const float* __restrict__ w_out,
    unsigned short* __restrict__ o_in, unsigned short* __restrict__ o_xp, unsigned short* __restrict__ o_out)
{
  int i = blockIdx.x * 256 + threadIdx.x;
  if (i < 1024*256) o_in[i]  = f2bf(w_in[i]);
  if (i < 48*512)   o_xp[i]  = f2bf(w_xp[i]);
  if (i < 256*512)  o_out[i] = f2bf(w_out[i]);
}

// ---------------- gemm1: xw = x @ w_gcn, stored TILED bf16 [m>>3][n][m&7] ----------------
__global__ __launch_bounds__(256) void gemm1_kernel(
    const float* __restrict__ x, const float* __restrict__ w, unsigned short* __restrict__ xwT2)
{
  __shared__ float xs[16*128];
  const int t = threadIdx.x;
  const int m0 = blockIdx.x * 16;
  {
    int r = t >> 4, c0 = (t & 15) * 8;
    const float* src = x + (size_t)(m0 + r)*FIN + c0;
    *(float4*)&xs[r*128 + c0]     = *(const float4*)src;
    *(float4*)&xs[r*128 + c0 + 4] = *(const float4*)(src + 4);
  }
  __syncthreads();
  const int n = t;
  float acc[16];
  #pragma unroll
  for (int m = 0; m < 16; ++m) acc[m] = 0.f;
  for (int k = 0; k < 128; k += 4){
    float w0 = w[(size_t)k*DM + n];
    float w1 = w[(size_t)(k+1)*DM + n];
    float w2 = w[(size_t)(k+2)*DM + n];
    float w3 = w[(size_t)(k+3)*DM + n];
    #pragma unroll
    for (int m = 0; m < 16; ++m){
      float4 xv = *(const float4*)&xs[m*128 + k];
      acc[m] = fmaf(xv.x, w0, acc[m]);
      acc[m] = fmaf(xv.y, w1, acc[m]);
      acc[m] = fmaf(xv.z, w2, acc[m]);
      acc[m] = fmaf(xv.w, w3, acc[m]);
    }
  }
  unsigned outp[8];
  #pragma unroll
  for (int m = 0; m < 8; ++m) outp[m] = pack2(acc[2*m], acc[2*m+1]);
  unsigned short* dst = xwT2 + (size_t)(m0 >> 3)*2048 + n*8;
  *(uint4*)dst          = *(uint4*)&outp[0];
  *(uint4*)(dst + 2048) = *(uint4*)&outp[4];
}

// ---------------- gemm2: hp[ks] = adj[:, ks-half] @ xw[ks-half, :] ----------------
// Pure register-pipelined: NO LDS, NO DMA, NO barriers. A fp32 direct (full-line
// coalesced, L1 dedups the 4 N-waves); B from tiled xwT2 (256B contiguous per frag).
// Compiler software-pipelines with fine-grained vmcnt. M64 N256 BK32, K-split 2.
__global__ __launch_bounds__(512, 1) void gemm2_kernel(
    const float* __restrict__ adj, const unsigned short* __restrict__ xwT2,
    float* __restrict__ hp)
{
  const int t = threadIdx.x;
  const int wave = t >> 6, lane = t & 63, r = lane & 15, q = lane >> 4;
  const int wm = wave & 1, wn = wave >> 1;
  const int mt = (int)blockIdx.x >> 1, ks = (int)blockIdx.x & 1;
  const int m0 = mt * 64;
  const int kb = ks * 4096;

  const float* ap0 = adj + (size_t)(m0 + wm*32 + r)*NN + kb + q*8;
  const float* ap1 = ap0 + (size_t)16*NN;
  const unsigned short* bp[4];
  #pragma unroll
  for (int ni = 0; ni < 4; ++ni)
    bp[ni] = xwT2 + ((size_t)(kb >> 3) + q)*2048 + (size_t)(wn*64 + ni*16 + r)*8;

  f32x4 acc[2][4];
  #pragma unroll
  for (int mi = 0; mi < 2; ++mi)
    #pragma unroll
    for (int ni = 0; ni < 4; ++ni) acc[mi][ni] = zero4();

  #pragma unroll 4
  for (int it = 0; it < 128; ++it){
    float4 a00 = *(const float4*)(ap0 + it*32);
    float4 a01 = *(const float4*)(ap0 + it*32 + 4);
    float4 a10 = *(const float4*)(ap1 + it*32);
    float4 a11 = *(const float4*)(ap1 + it*32 + 4);
    FragU fb[4];
    #pragma unroll
    for (int ni = 0; ni < 4; ++ni)
      fb[ni].u4 = *(const uint4*)(bp[ni] + (size_t)it*8192);
    FragU fa0, fa1;
    fa0.u[0] = pack2rn(a00.x, a00.y); fa0.u[1] = pack2rn(a00.z, a00.w);
    fa0.u[2] = pack2rn(a01.x, a01.y); fa0.u[3] = pack2rn(a01.z, a01.w);
    fa1.u[0] = pack2rn(a10.x, a10.y); fa1.u[1] = pack2rn(a10.z, a10.w);
    fa1.u[2] = pack2rn(a11.x, a11.y); fa1.u[3] = pack2rn(a11.z, a11.w);
    #pragma unroll
    for (int ni = 0; ni < 4; ++ni){
      acc[0][ni] = __builtin_amdgcn_mfma_f32_16x16x32_bf16(fa0.v, fb[ni].v, acc[0][ni], 0, 0, 0);
      acc[1][ni] = __builtin_amdgcn_mfma_f32_16x16x32_bf16(fa1.v, fb[ni].v, acc[1][ni], 0, 0, 0);
    }
  }

  float* hpo = hp + (size_t)ks * ((size_t)NN * DM);
  #pragma unroll
  for (int mi = 0; mi < 2; ++mi)
    #pragma unroll
    for (int ni = 0; ni < 4; ++ni){
      const int n = wn*64 + ni*16 + r;
      #pragma unroll
      for (int jr = 0; jr < 4; ++jr){
        const int m = m0 + wm*32 + mi*16 + q*4 + jr;
        hpo[(size_t)m*DM + n] = acc[mi][ni][jr];
      }
    }
}

// ---------------- hred: h = relu(hp0+hp1+bias) -> bf16, + BN stats ----------------
__global__ __launch_bounds__(256) void hred_kernel(
    const float* __restrict__ hp, const float* __restrict__ b_gcn,
    unsigned short* __restrict__ hb, float* __restrict__ bns, float* __restrict__ bns2)
{
  const size_t NND = (size_t)NN * DM;
  const int c = threadIdx.x;
  const int m0 = blockIdx.x * 32;
  const float bias = b_gcn[c];
  float s1 = 0.f, s2 = 0.f;
  #pragma unroll 8
  for (int rr = 0; rr < 32; ++rr){
    size_t idx = (size_t)(m0 + rr)*DM + c;
    float v = hp[idx] + hp[NND + idx] + bias;
    v = fmaxf(v, 0.f);
    hb[idx] = f2bf(v);
    s1 += v; s2 += v*v;
  }
  atomicAdd(bns + c, s1);
  atomicAdd(bns2 + c, s2);
}

// ---------------- wprep2: fold BN into w_in (W' = W*a[c], bias' = b @ W^T), emit a,b ----------------
__global__ __launch_bounds__(256) void wprep2_kernel(
    const float* __restrict__ bns, const float* __restrict__ bns2,
    const float* __restrict__ gamma, const float* __restrict__ beta,
    const unsigned short* __restrict__ winb,
    unsigned short* __restrict__ win2, float* __restrict__ binb, float* __restrict__ ab)
{
  __shared__ float as_[256], bs_[256];
  const int t = threadIdx.x;
  const int n0 = blockIdx.x * 32;
  float mean = bns[t] * (1.f/NN);
  float var  = bns2[t] * (1.f/NN) - mean*mean;
  float inv  = rsqrtf(var + 1e-5f);
  float a = inv * gamma[t];
  float b = beta[t] - mean * a;
  as_[t] = a; bs_[t] = b;
  if (blockIdx.x == 0){ ab[t] = a; ab[256 + t] = b; }
  __syncthreads();
  for (int rr = 0; rr < 32; ++rr){
    size_t idx = (size_t)(n0 + rr)*256 + t;
    win2[idx] = f2bf(bf2f(winb[idx]) * as_[t]);
  }
  const int wv = t >> 6, ln = t & 63;
  for (int pass = 0; pass < 8; ++pass){
    int row = n0 + pass*4 + wv;
    float v = 0.f;
    #pragma unroll
    for (int j = 0; j < 4; ++j){
      int c = ln*4 + j;
      v += bs_[c] * bf2f(winb[(size_t)row*256 + c]);
    }
    v += __shfl_xor(v, 1);  v += __shfl_xor(v, 2);  v += __shfl_xor(v, 4);
    v += __shfl_xor(v, 8);  v += __shfl_xor(v, 16); v += __shfl_xor(v, 32);
    if (ln == 0) binb[row] = v;
  }
}

// ---------------- gemm3: [xm|z] = hb @ W'^T + bias' (M=8192,K=256,N=1024), bf16 out ----------------
__global__ __launch_bounds__(256) void gemm3_kernel(
    const unsigned short* __restrict__ Ab, const unsigned short* __restrict__ Wb,
    const float* __restrict__ binb,
    unsigned short* __restrict__ xmb, unsigned short* __restrict__ zb)
{
  __shared__ uint4 alds[2048];  // 64 rows x 32 slots (swizzled), 32 KB
  const int t = threadIdx.x;
  const int wave = t >> 6, lane = t & 63, r = lane & 15, q = lane >> 4;
  const int mb = ((int)blockIdx.x & 127) * 64;
  const int nb = ((int)blockIdx.x >> 7) * 128;
  const int wm = wave & 1, wn = wave >> 1;

  #pragma unroll
  for (int j = 0; j < 8; ++j){
    int si = j*256 + t;
    int row = si >> 5, dg = si & 31;
    int sg = dg ^ (row & 31);
    ASYNC16(Ab + (size_t)(mb + row)*DM + sg*8, (char*)alds + si*16);
  }
  __syncthreads();

  f32x4 acc[2][4];
  #pragma unroll
  for (int mi = 0; mi < 2; ++mi)
    #pragma unroll
    for (int ni = 0; ni < 4; ++ni) acc[mi][ni] = zero4();

  const unsigned short* bp[4];
  #pragma unroll
  for (int ni = 0; ni < 4; ++ni)
    bp[ni] = Wb + (size_t)(nb + wn*64 + ni*16 + r)*DM + q*8;
  FragU fb[4];
  #pragma unroll
  for (int ni = 0; ni < 4; ++ni) fb[ni].u4 = *(const uint4*)bp[ni];

  #pragma unroll
  for (int it = 0; it < 8; ++it){
    FragU fbn[4];
    if (it < 7){
      #pragma unroll
      for (int ni = 0; ni < 4; ++ni) fbn[ni].u4 = *(const uint4*)(bp[ni] + (it+1)*32);
    }
    FragU fa[2];
    #pragma unroll
    for (int mi = 0; mi < 2; ++mi){
      int row = wm*32 + mi*16 + r;
      int g = it*4 + q;
      fa[mi].u4 = alds[row*32 + (g ^ (row & 31))];
    }
    #pragma unroll
    for (int mi = 0; mi < 2; ++mi)
      #pragma unroll
      for (int ni = 0; ni < 4; ++ni)
        acc[mi][ni] = __builtin_amdgcn_mfma_f32_16x16x32_bf16(fa[mi].v, fb[ni].v, acc[mi][ni], 0, 0, 0);
    if (it < 7){
      #pragma unroll
      for (int ni = 0; ni < 4; ++ni) fb[ni] = fbn[ni];
    }
  }
  #pragma unroll
  for (int mi = 0; mi < 2; ++mi)
    #pragma unroll
    for (int ni = 0; ni < 4; ++ni){
      int nc = nb + wn*64 + ni*16 + r;
      float bias = binb[nc];
      unsigned short* dst = (nc < 512) ? (xmb + nc) : (zb + (nc - 512));
      #pragma unroll
      for (int jr = 0; jr < 4; ++jr){
        int m = mb + wm*32 + mi*16 + q*4 + jr;
        dst[(size_t)m*DI] = f2bf(acc[mi][ni][jr] + bias);
      }
    }
}

// ---------------- conv: depthwise causal D=4 + SiLU, bf16 out ----------------
__global__ __launch_bounds__(256) void conv_kernel(
    const unsigned short* __restrict__ xmb, const float* __restrict__ conv_w, const float* __restrict__ conv_b,
    unsigned short* __restrict__ xcb)
{
  const int d0 = threadIdx.x * 2;
  const int n0 = blockIdx.x * 32;
  float4 wa = *(const float4*)(conv_w + (size_t)d0*4);
  float4 wb = *(const float4*)(conv_w + (size_t)d0*4 + 4);
  float2 bias = *(const float2*)(conv_b + d0);
  float x0a=0.f,x1a=0.f,x2a=0.f, x0b=0.f,x1b=0.f,x2b=0.f;
  #pragma unroll
  for (int j = 0; j < 3; ++j){
    int n = n0 - 3 + j;
    float va = 0.f, vb = 0.f;
    if (n >= 0){
      ushort2 u = *(const ushort2*)(xmb + (size_t)n*DI + d0);
      va = bf2f(u.x); vb = bf2f(u.y);
    }
    if (j == 0){ x0a = va; x0b = vb; }
    else if (j == 1){ x1a = va; x1b = vb; }
    else { x2a = va; x2b = vb; }
  }
  for (int j = 0; j < 32; ++j){
    int n = n0 + j;
    ushort2 u = *(const ushort2*)(xmb + (size_t)n*DI + d0);
    float x3a = bf2f(u.x), x3b = bf2f(u.y);
    float sa = bias.x + wa.x*x0a + wa.y*x1a + wa.z*x2a + wa.w*x3a;
    float sb = bias.y + wb.x*x0b + wb.y*x1b + wb.z*x2b + wb.w*x3b;
    float va = sa * sigmoidf_(sa);
    float vb = sb * sigmoidf_(sb);
    ushort2 o; o.x = f2bf(va); o.y = f2bf(vb);
    *(ushort2*)(xcb + (size_t)n*DI + d0) = o;
    x0a=x1a; x1a=x2a; x2a=x3a;
    x0b=x1b; x1b=x2b; x2b=x3b;
  }
}

// ---------------- gemm4: x_dbl = xc @ w_xproj^T (M=8192,K=512,N=48) + fused dt ----------------
__global__ __launch_bounds__(256) void gemm4_kernel(
    const unsigned short* __restrict__ Ab, const unsigned short* __restrict__ Wb,
    const float* __restrict__ w_dt, const float* __restrict__ b_dt,
    float* __restrict__ xdbl, float* __restrict__ dt)
{
  __shared__ uint4 alds[2048];  // 32 rows x 64 slots, 32 KB
  __shared__ float xr2[32*16];  // dt_r staging
  const int t = threadIdx.x;
  const int wave = t >> 6, lane = t & 63, r = lane & 15, q = lane >> 4;
  const int m0 = (int)blockIdx.x * 32;
  #pragma unroll
  for (int j = 0; j < 8; ++j){
    int si = j*256 + t;
    int row = si >> 6, dg = si & 63;
    int sg = dg ^ (row & 31);
    ASYNC16(Ab + (size_t)(m0 + row)*DI + sg*8, (char*)alds + si*16);
  }
  __syncthreads();
  f32x4 acc[2][3];
  #pragma unroll
  for (int mi = 0; mi < 2; ++mi)
    #pragma unroll
    for (int ni = 0; ni < 3; ++ni) acc[mi][ni] = zero4();
  const int kq = wave * 128;
  const unsigned short* bp[3];
  #pragma unroll
  for (int ni = 0; ni < 3; ++ni) bp[ni] = Wb + (size_t)(ni*16 + r)*DI + kq + q*8;
  FragU fb[3];
  #pragma unroll
  for (int ni = 0; ni < 3; ++ni) fb[ni].u4 = *(const uint4*)bp[ni];
  #pragma unroll
  for (int it = 0; it < 4; ++it){
    FragU fbn[3];
    if (it < 3){
      #pragma unroll
      for (int ni = 0; ni < 3; ++ni) fbn[ni].u4 = *(const uint4*)(bp[ni] + (it+1)*32);
    }
    FragU fa[2];
    #pragma unroll
    for (int mi = 0; mi < 2; ++mi){
      int row = mi*16 + r;
      int g = (kq >> 3) + it*4 + q;
      fa[mi].u4 = alds[row*64 + (g ^ (row & 31))];
    }
    #pragma unroll
    for (int mi = 0; mi < 2; ++mi)
      #pragma unroll
      for (int ni = 0; ni < 3; ++ni)
        acc[mi][ni] = __builtin_amdgcn_mfma_f32_16x16x32_bf16(fa[mi].v, fb[ni].v, acc[mi][ni], 0, 0, 0);
    if (it < 3){
      #pragma unroll
      for (int ni = 0; ni < 3; ++ni) fb[ni] = fbn[ni];
    }
  }
  __syncthreads();
  float* red = (float*)alds;
  if (wave > 0){
    int base = ((wave - 1)*64 + lane)*24;
    #pragma unroll
    for (int mi = 0; mi < 2; ++mi)
      #pragma unroll
      for (int ni = 0; ni < 3; ++ni)
        #pragma unroll
        for (int jr = 0; jr < 4; ++jr)
          red[base + (mi*3 + ni)*4 + jr] = acc[mi][ni][jr];
  }
  __syncthreads();
  if (wave == 0){
    #pragma unroll
    for (int w = 0; w < 3; ++w){
      int base = (w*64 + lane)*24;
      #pragma unroll
      for (int mi = 0; mi < 2; ++mi)
        #pragma unroll
        for (int ni = 0; ni < 3; ++ni)
          #pragma unroll
          for (int jr = 0; jr < 4; ++jr)
            acc[mi][ni][jr] += red[base + (mi*3 + ni)*4 + jr];
    }
    #pragma unroll
    for (int mi = 0; mi < 2; ++mi)
      #pragma unroll
      for (int ni = 0; ni < 3; ++ni)
        #pragma unroll
        for (int jr = 0; jr < 4; ++jr)
          xdbl[(size_t)(m0 + mi*16 + q*4 + jr)*48 + ni*16 + r] = acc[mi][ni][jr];
    #pragma unroll
    for (int mi = 0; mi < 2; ++mi)
      #pragma unroll
      for (int jr = 0; jr < 4; ++jr)
        xr2[(mi*16 + q*4 + jr)*16 + r] = acc[mi][0][jr];
  }
  __syncthreads();
  const int d0 = t * 2;
  const float4* wp0 = (const float4*)(w_dt + (size_t)d0*16);
  const float4* wp1 = (const float4*)(w_dt + (size_t)(d0+1)*16);
  float4 wA0 = wp0[0], wA1 = wp0[1], wA2 = wp0[2], wA3 = wp0[3];
  float4 wB0 = wp1[0], wB1 = wp1[1], wB2 = wp1[2], wB3 = wp1[3];
  float2 bb = *(const float2*)(b_dt + d0);
  for (int j = 0; j < 32; ++j){
    const float4* xp = (const float4*)(xr2 + j*16);
    float4 a0 = xp[0], a1 = xp[1], a2 = xp[2], a3 = xp[3];
    float sA = bb.x, sB = bb.y;
    sA += wA0.x*a0.x + wA0.y*a0.y + wA0.z*a0.z + wA0.w*a0.w;
    sA += wA1.x*a1.x + wA1.y*a1.y + wA1.z*a1.z + wA1.w*a1.w;
    sA += wA2.x*a2.x + wA2.y*a2.y + wA2.z*a2.z + wA2.w*a2.w;
    sA += wA3.x*a3.x + wA3.y*a3.y + wA3.z*a3.z + wA3.w*a3.w;
    sB += wB0.x*a0.x + wB0.y*a0.y + wB0.z*a0.z + wB0.w*a0.w;
    sB += wB1.x*a1.x + wB1.y*a1.y + wB1.z*a1.z + wB1.w*a1.w;
    sB += wB2.x*a2.x + wB2.y*a2.y + wB2.z*a2.z + wB2.w*a2.w;
    sB += wB3.x*a3.x + wB3.y*a3.y + wB3.z*a3.z + wB3.w*a3.w;
    float oA = (sA > 20.f) ? sA : log1pf(__expf(sA));
    float oB = (sB > 20.f) ? sB : log1pf(__expf(sB));
    *(float2*)(dt + (size_t)(m0 + j)*DI + d0) = make_float2(oA, oB);
  }
}

// ---------------- scanA: per-chunk local recurrence -> interleaved {P,F} ----------------
__global__ __launch_bounds__(256) void scanA_kernel(
    const float* __restrict__ dt, const unsigned short* __restrict__ xcb,
    const float* __restrict__ xdbl, const float* __restrict__ A_log,
    float2* __restrict__ PF)
{
  __shared__ float Bs[CL*DST];
  const int t = threadIdx.x;
  const int c = (int)blockIdx.x >> 1;
  const int d = (((int)blockIdx.x & 1) << 8) + t;
  #pragma unroll
  for (int j = 0; j < 2; ++j){
    int idx = t + 256*j;
    Bs[idx] = xdbl[(size_t)(c*CL + (idx >> 4))*48 + 16 + (idx & 15)];
  }
  __syncthreads();
  float Av[DST], hs[DST];
  {
    const float4* Ap = (const float4*)(A_log + (size_t)d*DST);
    #pragma unroll
    for (int s4 = 0; s4 < 4; ++s4){
      float4 a4 = Ap[s4];
      Av[s4*4+0] = -__expf(a4.x); Av[s4*4+1] = -__expf(a4.y);
      Av[s4*4+2] = -__expf(a4.z); Av[s4*4+3] = -__expf(a4.w);
    }
  }
  #pragma unroll
  for (int s = 0; s < DST; ++s) hs[s] = 0.f;
  float sdt = 0.f;
  const size_t rb = (size_t)c*CL*DI + d;
  float dtv = dt[rb], xcv = bf2f(xcb[rb]);
  for (int tt = 0; tt < CL; ++tt){
    float dtn = 0.f, xcn = 0.f;
    if (tt + 1 < CL){
      dtn = dt[rb + (size_t)(tt+1)*DI];
      xcn = bf2f(xcb[rb + (size_t)(tt+1)*DI]);
    }
    float u = dtv * xcv;
    sdt += dtv;
    float bv[DST];
    *(float4*)&bv[0]  = *(const float4*)&Bs[tt*16];
    *(float4*)&bv[4]  = *(const float4*)&Bs[tt*16 + 4];
    *(float4*)&bv[8]  = *(const float4*)&Bs[tt*16 + 8];
    *(float4*)&bv[12] = *(const float4*)&Bs[tt*16 + 12];
    #pragma unroll
    for (int s = 0; s < DST; ++s)
      hs[s] = __expf(dtv * Av[s]) * hs[s] + u * bv[s];
    dtv = dtn; xcv = xcn;
  }
  float4* out = (float4*)(PF + (size_t)c*(DI*DST) + (size_t)d*DST);
  #pragma unroll
  for (int j = 0; j < 8; ++j){
    float4 v;
    v.x = __expf(Av[2*j] * sdt);   v.y = hs[2*j];
    v.z = __expf(Av[2*j+1] * sdt); v.w = hs[2*j+1];
    out[j] = v;
  }
}

// ---------------- scanB: sequential carry across 256 chunks ----------------
__global__ __launch_bounds__(64) void scanB_kernel(
    const float2* __restrict__ PF, float* __restrict__ Cy)
{
  const int ds = (int)blockIdx.x*64 + (int)threadIdx.x;
  float2 A0[16], A1[16];
  #pragma unroll
  for (int j = 0; j < 16; ++j) A0[j] = PF[(size_t)j*8192 + ds];
  #pragma unroll
  for (int j = 0; j < 16; ++j) A1[j] = PF[(size_t)(16 + j)*8192 + ds];
  float cy = 0.f;
  Cy[ds] = 0.f;
  #pragma unroll
  for (int g = 0; g < 16; ++g){
    #pragma unroll
    for (int j = 0; j < 16; ++j){
      int i = g*16 + j;
      if (i < NC - 1){
        float2 pf = (g & 1) ? A1[j] : A0[j];
        cy = pf.x * cy + pf.y;
        Cy[(size_t)(i + 1)*8192 + ds] = cy;
      }
    }
    int gn = g + 2;
    if (gn < 16){
      #pragma unroll
      for (int j = 0; j < 16; ++j){
        float2 v = PF[(size_t)(gn*16 + j)*8192 + ds];
        if (g & 1) A1[j] = v; else A0[j] = v;
      }
    }
  }
}

// ---------------- scanC: recompute with carry, emit gated y (bf16) ----------------
__global__ __launch_bounds__(256) void scanC_kernel(
    const float* __restrict__ dt, const unsigned short* __restrict__ xcb,
    const float* __restrict__ xdbl, const float* __restrict__ A_log,
    const float* __restrict__ Cy, const float* __restrict__ Dskip,
    const unsigned short* __restrict__ zb, unsigned short* __restrict__ yb)
{
  __shared__ float Bs[CL*DST];
  __shared__ float Cs[CL*DST];
  const int t = threadIdx.x;
  const int c = (int)blockIdx.x >> 1;
  const int d = (((int)blockIdx.x & 1) << 8) + t;
  #pragma unroll
  for (int j = 0; j < 2; ++j){
    int idx = t + 256*j;
    int tg = c*CL + (idx >> 4);
    Bs[idx] = xdbl[(size_t)tg*48 + 16 + (idx & 15)];
    Cs[idx] = xdbl[(size_t)tg*48 + 32 + (idx & 15)];
  }
  __syncthreads();
  float Av[DST], hs[DST];
  {
    const float4* Ap = (const float4*)(A_log + (size_t)d*DST);
    #pragma unroll
    for (int s4 = 0; s4 < 4; ++s4){
      float4 a4 = Ap[s4];
      Av[s4*4+0] = -__expf(a4.x); Av[s4*4+1] = -__expf(a4.y);
      Av[s4*4+2] = -__expf(a4.z); Av[s4*4+3] = -__expf(a4.w);
    }
  }
  {
    const float4* hp4 = (const float4*)(Cy + (size_t)c*(DI*DST) + (size_t)d*DST);
    #pragma unroll
    for (int s4 = 0; s4 < 4; ++s4){
      float4 h4 = hp4[s4];
      hs[s4*4+0] = h4.x; hs[s4*4+1] = h4.y; hs[s4*4+2] = h4.z; hs[s4*4+3] = h4.w;
    }
  }
  const float Dv = Dskip[d];
  const size_t rb = (size_t)c*CL*DI + d;
  float dtv = dt[rb], xcv = bf2f(xcb[rb]);
  unsigned short zv0 = zb[rb];
  for (int tt = 0; tt < CL; ++tt){
    float dtn = 0.f, xcn = 0.f;
    unsigned short zn = 0;
    if (tt + 1 < CL){
      dtn = dt[rb + (size_t)(tt+1)*DI];
      xcn = bf2f(xcb[rb + (size_t)(tt+1)*DI]);
      zn  = zb[rb + (size_t)(tt+1)*DI];
    }
    float u = dtv * xcv;
    float bv[DST], cv[DST];
    *(float4*)&bv[0]  = *(const float4*)&Bs[tt*16];
    *(float4*)&bv[4]  = *(const float4*)&Bs[tt*16 + 4];
    *(float4*)&bv[8]  = *(const float4*)&Bs[tt*16 + 8];
    *(float4*)&bv[12] = *(const float4*)&Bs[tt*16 + 12];
    *(float4*)&cv[0]  = *(const float4*)&Cs[tt*16];
    *(float4*)&cv[4]  = *(const float4*)&Cs[tt*16 + 4];
    *(float4*)&cv[8]  = *(const float4*)&Cs[tt*16 + 8];
    *(float4*)&cv[12] = *(const float4*)&Cs[tt*16 + 12];
    float y0 = 0.f, y1 = 0.f;
    #pragma unroll
    for (int s = 0; s < DST; s += 2){
      hs[s]   = __expf(dtv * Av[s])   * hs[s]   + u * bv[s];
      hs[s+1] = __expf(dtv * Av[s+1]) * hs[s+1] + u * bv[s+1];
      y0 += hs[s]   * cv[s];
      y1 += hs[s+1] * cv[s+1];
    }
    float z = bf2f(zv0);
    float yf = ((y0 + y1) + Dv * xcv) * (z * sigmoidf_(z));
    yb[rb + (size_t)tt*DI] = f2bf(yf);
    dtv = dtn; xcv = xcn; zv0 = zn;
  }
}

// ---------------- gemm5: out = y @ w_out^T + (hb*a + b) (M=8192,K=512,N=256) ----------------
__global__ __launch_bounds__(512) void gemm5_kernel(
    const unsigned short* __restrict__ yb, const unsigned short* __restrict__ Wb,
    const unsigned short* __restrict__ hb, const float* __restrict__ ab,
    float* __restrict__ out)
{
  __shared__ uint4 alds[2048];  // 32 rows x 64 slots, 32 KB
  const int t = threadIdx.x;
  const int wave = t >> 6, lane = t & 63, r = lane & 15, q = lane >> 4;
  const int m0 = (int)blockIdx.x * 32;
  #pragma unroll
  for (int j = 0; j < 4; ++j){
    int si = j*512 + t;
    int row = si >> 6, dg = si & 63;
    int sg = dg ^ (row & 31);
    ASYNC16(yb + (size_t)(m0 + row)*DI + sg*8, (char*)alds + si*16);
  }
  __syncthreads();
  f32x4 acc[2][2];
  #pragma unroll
  for (int mi = 0; mi < 2; ++mi)
    #pragma unroll
    for (int ni = 0; ni < 2; ++ni) acc[mi][ni] = zero4();
  const int nw = wave * 32;
  const unsigned short* bp0 = Wb + (size_t)(nw + r)*DI + q*8;
  const unsigned short* bp1 = Wb + (size_t)(nw + 16 + r)*DI + q*8;
  FragU fb0, fb1;
  fb0.u4 = *(const uint4*)bp0;
  fb1.u4 = *(const uint4*)bp1;
  #pragma unroll
  for (int it = 0; it < 16; ++it){
    FragU fn0, fn1;
    if (it < 15){
      fn0.u4 = *(const uint4*)(bp0 + (it+1)*32);
      fn1.u4 = *(const uint4*)(bp1 + (it+1)*32);
    }
    FragU fa[2];
    #pragma unroll
    for (int mi = 0; mi < 2; ++mi){
      int row = mi*16 + r;
      int g = it*4 + q;
      fa[mi].u4 = alds[row*64 + (g ^ (row & 31))];
    }
    acc[0][0] = __builtin_amdgcn_mfma_f32_16x16x32_bf16(fa[0].v, fb0.v, acc[0][0], 0, 0, 0);
    acc[0][1] = __builtin_amdgcn_mfma_f32_16x16x32_bf16(fa[0].v, fb1.v, acc[0][1], 0, 0, 0);
    acc[1][0] = __builtin_amdgcn_mfma_f32_16x16x32_bf16(fa[1].v, fb0.v, acc[1][0], 0, 0, 0);
    acc[1][1] = __builtin_amdgcn_mfma_f32_16x16x32_bf16(fa[1].v, fb1.v, acc[1][1], 0, 0, 0);
    if (it < 15){ fb0 = fn0; fb1 = fn1; }
  }
  #pragma unroll
  for (int mi = 0; mi < 2; ++mi)
    #pragma unroll
    for (int ni = 0; ni < 2; ++ni){
      const int n = nw + ni*16 + r;
      const float aA = ab[n], bB = ab[256 + n];
      #pragma unroll
      for (int jr = 0; jr < 4; ++jr){
        const int m = m0 + mi*16 + q*4 + jr;
        size_t idx = (size_t)m*DM + n;
        out[idx] = acc[mi][ni][jr] + bf2f(hb[idx])*aA + bB;
      }
    }
}

// ---------------- launch ----------------
extern "C" void kernel_launch(void* const* d_in, const int* in_sizes, int n_in,
                              void* d_out, int out_size, void* d_ws, size_t ws_size,
                              hipStream_t stream)
{
  const float* x      = (const float*)d_in[0];
  const float* adj    = (const float*)d_in[1];
  const float* w_gcn  = (const float*)d_in[2];
  const float* b_gcn  = (const float*)d_in[3];
  const float* gamma  = (const float*)d_in[4];
  const float* beta   = (const float*)d_in[5];
  const float* w_in   = (const float*)d_in[6];
  const float* conv_w = (const float*)d_in[7];
  const float* conv_b = (const float*)d_in[8];
  const float* w_xp   = (const float*)d_in[9];
  const float* w_dt   = (const float*)d_in[10];
  const float* b_dt   = (const float*)d_in[11];
  const float* A_log  = (const float*)d_in[12];
  const float* D_skip = (const float*)d_in[13];
  const float* w_out  = (const float*)d_in[14];
  float* out = (float*)d_out;
  char* ws = (char*)d_ws;
  if (ws_size < WS_NEED) return;

  unsigned short* xwT2  = (unsigned short*)(ws + OFF_XWT);
  float*          hp    = (float*)(ws + OFF_HP);
  unsigned short* hb    = (unsigned short*)(ws + OFF_HB);
  unsigned short* winb  = (unsigned short*)(ws + OFF_WINB);
  unsigned short* win2  = (unsigned short*)(ws + OFF_WIN2);
  float*          binb  = (float*)(ws + OFF_BIN);
  float*          ab    = (float*)(ws + OFF_AB);
  unsigned short* wxpb  = (unsigned short*)(ws + OFF_WXPB);
  unsigned short* woutb = (unsigned short*)(ws + OFF_WOUTB);
  unsigned short* xmb   = (unsigned short*)(ws + OFF_XMB);
  unsigned short* zb    = (unsigned short*)(ws + OFF_ZB);
  unsigned short* xcb   = (unsigned short*)(ws + OFF_XCB);
  float*          xdbl  = (float*)(ws + OFF_XDBL);
  float*          dtb   = (float*)(ws + OFF_DT);
  float2*         PF    = (float2*)(ws + OFF_PF);
  float*          Cy    = (float*)(ws + OFF_CY);
  unsigned short* yb    = (unsigned short*)(ws + OFF_YB);
  float*          bns   = (float*)(ws + OFF_BNS);
  float*          bns2  = (float*)(ws + OFF_BNS2);

  hipMemsetAsync(bns, 0, 2*256*sizeof(float), stream);

  prep_kernel   <<<1024, 256, 0, stream>>>(w_in, w_xp, w_out, winb, wxpb, woutb);
  gemm1_kernel  <<<512,  256, 0, stream>>>(x, w_gcn, xwT2);
  gemm2_kernel  <<<256,  512, 0, stream>>>(adj, xwT2, hp);
  hred_kernel   <<<256,  256, 0, stream>>>(hp, b_gcn, hb, bns, bns2);
  wprep2_kernel <<<32,   256, 0, stream>>>(bns, bns2, gamma, beta, winb, win2, binb, ab);
  gemm3_kernel  <<<1024, 256, 0, stream>>>(hb, win2, binb, xmb, zb);
  conv_kernel   <<<256,  256, 0, stream>>>(xmb, conv_w, conv_b, xcb);
  gemm4_kernel  <<<256,  256, 0, stream>>>(xcb, wxpb, w_dt, b_dt, xdbl, dtb);
  scanA_kernel  <<<512,  256, 0, stream>>>(dtb, xcb, xdbl, A_log, PF);
  scanB_kernel  <<<128,  64,  0, stream>>>(PF, Cy);
  scanC_kernel  <<<512,  256, 0, stream>>>(dtb, xcb, xdbl, A_log, Cy, D_skip, zb, yb);
  gemm5_kernel  <<<256,  512, 0, stream>>>(yb, woutb, hb, ab, out);
}